// Round 1
// baseline (467.746 us; speedup 1.0000x reference)
//
#include <hip/hip_runtime.h>
#include <hip/hip_bf16.h>
#include <stdint.h>

#define H_DIM 2048
#define I_DIM 5632
#define M_DIM 8192
#define N1_DIM (2 * I_DIM)  // 11264

typedef __attribute__((ext_vector_type(4))) int i32x4;

__device__ __forceinline__ void gload16(const void* g, void* l) {
  __builtin_amdgcn_global_load_lds(
      reinterpret_cast<const __attribute__((address_space(1))) uint32_t*>(
          reinterpret_cast<uintptr_t>(g)),
      reinterpret_cast<__attribute__((address_space(3))) uint32_t*>(
          reinterpret_cast<uintptr_t>(l)),
      16, 0, 0);
}

// ---------------- per-row int8 quant of f32 matrix ----------------
__global__ __launch_bounds__(256) void quant_rows_f32(
    const float* __restrict__ in, int8_t* __restrict__ q,
    float* __restrict__ scl, int rowlen) {
  const int row = blockIdx.x;
  const int tid = threadIdx.x;
  const float* rp = in + (size_t)row * rowlen;
  float m = 0.f;
  for (int i = tid * 4; i < rowlen; i += 1024) {
    const float4 v = *reinterpret_cast<const float4*>(rp + i);
    m = fmaxf(m, fmaxf(fmaxf(fabsf(v.x), fabsf(v.y)),
                       fmaxf(fabsf(v.z), fabsf(v.w))));
  }
#pragma unroll
  for (int o = 32; o; o >>= 1) m = fmaxf(m, __shfl_xor(m, o));
  __shared__ float wm[4];
  if ((tid & 63) == 0) wm[tid >> 6] = m;
  __syncthreads();
  m = fmaxf(fmaxf(wm[0], wm[1]), fmaxf(wm[2], wm[3]));
  const float scale = fmaxf(m / 127.0f, 1e-8f);
  const float inv = 1.0f / scale;
  if (tid == 0) scl[row] = scale;
  int8_t* qp = q + (size_t)row * rowlen;
  for (int i = tid * 4; i < rowlen; i += 1024) {
    const float4 v = *reinterpret_cast<const float4*>(rp + i);
    const int a = (int)rintf(fminf(fmaxf(v.x * inv, -127.f), 127.f));
    const int b = (int)rintf(fminf(fmaxf(v.y * inv, -127.f), 127.f));
    const int c = (int)rintf(fminf(fmaxf(v.z * inv, -127.f), 127.f));
    const int d = (int)rintf(fminf(fmaxf(v.w * inv, -127.f), 127.f));
    *reinterpret_cast<int*>(qp + i) =
        (a & 255) | ((b & 255) << 8) | ((c & 255) << 16) | (d << 24);
  }
}

// ---------------- per-row int8 quant of bf16 h (exact f32 absmax supplied) ----
__global__ __launch_bounds__(256) void quant_h_rows(
    const __hip_bfloat16* __restrict__ h, const int* __restrict__ amax,
    int8_t* __restrict__ q, float* __restrict__ scl) {
  const int row = blockIdx.x;
  const int tid = threadIdx.x;
  const float scale = fmaxf(__int_as_float(amax[row]) / 127.0f, 1e-8f);
  const float inv = 1.0f / scale;
  if (tid == 0) scl[row] = scale;
  const __hip_bfloat16* rp = h + (size_t)row * I_DIM;
  int8_t* qp = q + (size_t)row * I_DIM;
  for (int i = tid * 8; i < I_DIM; i += 2048) {
    const uint4 v = *reinterpret_cast<const uint4*>(rp + i);
    const uint32_t w[4] = {v.x, v.y, v.z, v.w};
    int pk0 = 0, pk1 = 0;
#pragma unroll
    for (int j = 0; j < 8; ++j) {
      const float f =
          __uint_as_float(((w[j >> 1] >> ((j & 1) * 16)) & 0xffffu) << 16);
      const int qv = (int)rintf(fminf(fmaxf(f * inv, -127.f), 127.f));
      if (j < 4) pk0 |= (qv & 255) << ((j & 3) * 8);
      else       pk1 |= (qv & 255) << ((j & 3) * 8);
    }
    *reinterpret_cast<int2*>(qp + i) = make_int2(pk0, pk1);
  }
}

// ---------------- GEMM1 fused: gate/up int8 GEMM + SiLU -> h(bf16) + row absmax
__global__ __launch_bounds__(256) void gemm1_silu(
    const int8_t* __restrict__ qx, const float* __restrict__ sx,
    const int8_t* __restrict__ qw, const float* __restrict__ sw,
    __hip_bfloat16* __restrict__ h, int* __restrict__ hmax) {
  __shared__ int8_t lds[65536];  // A:2x16K, Bg:2x8K, Bu:2x8K
  const int tid = threadIdx.x;
  const int lane = tid & 63;
  const int wid = tid >> 6;
  const int bn = blockIdx.x;  // 88 tiles of 64 cols (gate & up)
  const int bm = blockIdx.y;  // 64 tiles of 128 rows

  const int lr = lane >> 3;                    // row-in-8 for staging
  const int swz = ((lane & 7) ^ lr) << 4;      // pre-swizzled global 16B slot
  const size_t loff = (size_t)lr * H_DIM + swz;

  const int8_t* Ag  = qx + (size_t)(bm * 128 + wid * 32) * H_DIM;
  const int8_t* Bgg = qw + (size_t)(bn * 64 + wid * 16) * H_DIM;
  const int8_t* Bug = qw + (size_t)(I_DIM + bn * 64 + wid * 16) * H_DIM;

  const int wr = wid >> 1, wc = wid & 1;
  const int c16 = lane & 15;
  const int kq = lane >> 4;
  const int r7 = lane & 7;

  i32x4 accg[4][2] = {};
  i32x4 accu[4][2] = {};

  auto stage = [&](int buf, int kt) {
    const int kb = kt * 128;
#pragma unroll
    for (int i = 0; i < 4; ++i)
      gload16(Ag + (size_t)i * 8 * H_DIM + kb + loff,
              lds + buf * 16384 + (wid * 32 + i * 8) * 128);
#pragma unroll
    for (int i = 0; i < 2; ++i)
      gload16(Bgg + (size_t)i * 8 * H_DIM + kb + loff,
              lds + 32768 + buf * 8192 + (wid * 16 + i * 8) * 128);
#pragma unroll
    for (int i = 0; i < 2; ++i)
      gload16(Bug + (size_t)i * 8 * H_DIM + kb + loff,
              lds + 49152 + buf * 8192 + (wid * 16 + i * 8) * 128);
  };

  stage(0, 0);
  __syncthreads();
  const int KT = H_DIM / 128;  // 16
  for (int kt = 0; kt < KT; ++kt) {
    const int cur = kt & 1;
    if (kt + 1 < KT) stage(cur ^ 1, kt + 1);
    const int8_t* Ab  = lds + cur * 16384;
    const int8_t* Bgb = lds + 32768 + cur * 8192;
    const int8_t* Bub = lds + 49152 + cur * 8192;
#pragma unroll
    for (int kk = 0; kk < 2; ++kk) {
      const int slot = ((kk * 4 + kq) ^ r7) << 4;
      i32x4 a[4], bg[2], bu[2];
#pragma unroll
      for (int m = 0; m < 4; ++m)
        a[m] = *reinterpret_cast<const i32x4*>(
            Ab + (wr * 64 + m * 16 + c16) * 128 + slot);
#pragma unroll
      for (int n = 0; n < 2; ++n) {
        bg[n] = *reinterpret_cast<const i32x4*>(
            Bgb + (wc * 32 + n * 16 + c16) * 128 + slot);
        bu[n] = *reinterpret_cast<const i32x4*>(
            Bub + (wc * 32 + n * 16 + c16) * 128 + slot);
      }
#pragma unroll
      for (int m = 0; m < 4; ++m)
#pragma unroll
        for (int n = 0; n < 2; ++n) {
          accg[m][n] =
              __builtin_amdgcn_mfma_i32_16x16x64_i8(a[m], bg[n], accg[m][n], 0, 0, 0);
          accu[m][n] =
              __builtin_amdgcn_mfma_i32_16x16x64_i8(a[m], bu[n], accu[m][n], 0, 0, 0);
        }
    }
    __syncthreads();
  }

  // epilogue: dequant (exact int * scale), silu(g)*u, write bf16 h, row absmax
  const int row0 = bm * 128 + wr * 64;
  const int col0 = bn * 64 + wc * 32;
#pragma unroll
  for (int m = 0; m < 4; ++m) {
#pragma unroll
    for (int r = 0; r < 4; ++r) {
      const int row = row0 + m * 16 + kq * 4 + r;
      const float sxr = sx[row];
      float rmax = 0.f;
#pragma unroll
      for (int n = 0; n < 2; ++n) {
        const int col = col0 + n * 16 + c16;
        const float g = (float)accg[m][n][r] * (sxr * sw[col]);
        const float u = (float)accu[m][n][r] * (sxr * sw[I_DIM + col]);
        const float hv = g / (1.f + __expf(-g)) * u;
        h[(size_t)row * I_DIM + col] = __float2bfloat16(hv);
        rmax = fmaxf(rmax, fabsf(hv));
      }
#pragma unroll
      for (int o = 1; o < 16; o <<= 1) rmax = fmaxf(rmax, __shfl_xor(rmax, o));
      if (c16 == 0) atomicMax(hmax + row, __float_as_int(rmax));
    }
  }
}

// ---------------- GEMM2: int8 GEMM, dequant -> f32 out ----------------
__global__ __launch_bounds__(256) void gemm2(
    const int8_t* __restrict__ qh, const float* __restrict__ sh,
    const int8_t* __restrict__ qw, const float* __restrict__ sw,
    float* __restrict__ out) {
  __shared__ int8_t lds[65536];  // A:2x16K, B:2x16K
  const int tid = threadIdx.x;
  const int lane = tid & 63;
  const int wid = tid >> 6;
  const int bn = blockIdx.x;  // 16 tiles of 128 cols
  const int bm = blockIdx.y;  // 64 tiles of 128 rows

  const int lr = lane >> 3;
  const int swz = ((lane & 7) ^ lr) << 4;
  const size_t loff = (size_t)lr * I_DIM + swz;

  const int8_t* Ag = qh + (size_t)(bm * 128 + wid * 32) * I_DIM;
  const int8_t* Bg = qw + (size_t)(bn * 128 + wid * 32) * I_DIM;

  const int wr = wid >> 1, wc = wid & 1;
  const int c16 = lane & 15;
  const int kq = lane >> 4;
  const int r7 = lane & 7;

  i32x4 acc[4][4] = {};

  auto stage = [&](int buf, int kt) {
    const int kb = kt * 128;
#pragma unroll
    for (int i = 0; i < 4; ++i)
      gload16(Ag + (size_t)i * 8 * I_DIM + kb + loff,
              lds + buf * 16384 + (wid * 32 + i * 8) * 128);
#pragma unroll
    for (int i = 0; i < 4; ++i)
      gload16(Bg + (size_t)i * 8 * I_DIM + kb + loff,
              lds + 32768 + buf * 16384 + (wid * 32 + i * 8) * 128);
  };

  stage(0, 0);
  __syncthreads();
  const int KT = I_DIM / 128;  // 44
  for (int kt = 0; kt < KT; ++kt) {
    const int cur = kt & 1;
    if (kt + 1 < KT) stage(cur ^ 1, kt + 1);
    const int8_t* Ab = lds + cur * 16384;
    const int8_t* Bb = lds + 32768 + cur * 16384;
#pragma unroll
    for (int kk = 0; kk < 2; ++kk) {
      const int slot = ((kk * 4 + kq) ^ r7) << 4;
      i32x4 a[4], b[4];
#pragma unroll
      for (int m = 0; m < 4; ++m)
        a[m] = *reinterpret_cast<const i32x4*>(
            Ab + (wr * 64 + m * 16 + c16) * 128 + slot);
#pragma unroll
      for (int n = 0; n < 4; ++n)
        b[n] = *reinterpret_cast<const i32x4*>(
            Bb + (wc * 64 + n * 16 + c16) * 128 + slot);
#pragma unroll
      for (int m = 0; m < 4; ++m)
#pragma unroll
        for (int n = 0; n < 4; ++n)
          acc[m][n] =
              __builtin_amdgcn_mfma_i32_16x16x64_i8(a[m], b[n], acc[m][n], 0, 0, 0);
    }
    __syncthreads();
  }

  const int row0 = bm * 128 + wr * 64;
  const int col0 = bn * 128 + wc * 64;
#pragma unroll
  for (int m = 0; m < 4; ++m) {
#pragma unroll
    for (int r = 0; r < 4; ++r) {
      const int row = row0 + m * 16 + kq * 4 + r;
      const float shr = sh[row];
#pragma unroll
      for (int n = 0; n < 4; ++n) {
        const int col = col0 + n * 16 + c16;
        out[(size_t)row * H_DIM + col] = (float)acc[m][n][r] * (shr * sw[col]);
      }
    }
  }
}

extern "C" void kernel_launch(void* const* d_in, const int* in_sizes, int n_in,
                              void* d_out, int out_size, void* d_ws, size_t ws_size,
                              hipStream_t stream) {
  (void)in_sizes; (void)n_in; (void)out_size; (void)ws_size;
  const float* x  = (const float*)d_in[0];
  const float* w1 = (const float*)d_in[1];
  const float* w2 = (const float*)d_in[2];
  float* out = (float*)d_out;

  size_t off = 0;
  auto alloc = [&](size_t n) {
    void* p = (char*)d_ws + off;
    off += (n + 255) & ~(size_t)255;
    return p;
  };
  int8_t* qx  = (int8_t*)alloc((size_t)M_DIM * H_DIM);        // 16 MiB
  int8_t* qw1 = (int8_t*)alloc((size_t)N1_DIM * H_DIM);       // 22 MiB
  int8_t* qw2 = (int8_t*)alloc((size_t)H_DIM * I_DIM);        // 11 MiB
  int8_t* qh  = (int8_t*)alloc((size_t)M_DIM * I_DIM);        // 44 MiB
  __hip_bfloat16* hb = (__hip_bfloat16*)alloc((size_t)M_DIM * I_DIM * 2);  // 88 MiB
  float* sx  = (float*)alloc((size_t)M_DIM * 4);
  float* sw1 = (float*)alloc((size_t)N1_DIM * 4);
  float* sw2 = (float*)alloc((size_t)H_DIM * 4);
  float* shs = (float*)alloc((size_t)M_DIM * 4);
  int* hmax  = (int*)alloc((size_t)M_DIM * 4);

  hipMemsetAsync(hmax, 0, (size_t)M_DIM * 4, stream);
  quant_rows_f32<<<M_DIM, 256, 0, stream>>>(x, qx, sx, H_DIM);
  quant_rows_f32<<<N1_DIM, 256, 0, stream>>>(w1, qw1, sw1, H_DIM);
  quant_rows_f32<<<H_DIM, 256, 0, stream>>>(w2, qw2, sw2, I_DIM);
  gemm1_silu<<<dim3(I_DIM / 64, M_DIM / 128), 256, 0, stream>>>(
      qx, sx, qw1, sw1, hb, hmax);
  quant_h_rows<<<M_DIM, 256, 0, stream>>>(hb, hmax, qh, shs);
  gemm2<<<dim3(H_DIM / 128, M_DIM / 128), 256, 0, stream>>>(
      qh, shs, qw2, sw2, out);
}

// Round 2
// 459.375 us; speedup vs baseline: 1.0182x; 1.0182x over previous
//
#include <hip/hip_runtime.h>
#include <hip/hip_bf16.h>
#include <stdint.h>

#define H_DIM 2048
#define I_DIM 5632
#define M_DIM 8192
#define N1_DIM (2 * I_DIM)  // 11264

typedef __attribute__((ext_vector_type(4))) int i32x4;

__device__ __forceinline__ void gload16(const void* g, void* l) {
  __builtin_amdgcn_global_load_lds(
      reinterpret_cast<const __attribute__((address_space(1))) uint32_t*>(
          reinterpret_cast<uintptr_t>(g)),
      reinterpret_cast<__attribute__((address_space(3))) uint32_t*>(
          reinterpret_cast<uintptr_t>(l)),
      16, 0, 0);
}

#define BAR()                                \
  do {                                       \
    asm volatile("" ::: "memory");           \
    __builtin_amdgcn_s_barrier();            \
    asm volatile("" ::: "memory");           \
  } while (0)

// ---------------- per-row int8 quant of f32 matrix ----------------
__global__ __launch_bounds__(256) void quant_rows_f32(
    const float* __restrict__ in, int8_t* __restrict__ q,
    float* __restrict__ scl, int rowlen) {
  const int row = blockIdx.x;
  const int tid = threadIdx.x;
  const float* rp = in + (size_t)row * rowlen;
  float m = 0.f;
  for (int i = tid * 4; i < rowlen; i += 1024) {
    const float4 v = *reinterpret_cast<const float4*>(rp + i);
    m = fmaxf(m, fmaxf(fmaxf(fabsf(v.x), fabsf(v.y)),
                       fmaxf(fabsf(v.z), fabsf(v.w))));
  }
#pragma unroll
  for (int o = 32; o; o >>= 1) m = fmaxf(m, __shfl_xor(m, o));
  __shared__ float wm[4];
  if ((tid & 63) == 0) wm[tid >> 6] = m;
  __syncthreads();
  m = fmaxf(fmaxf(wm[0], wm[1]), fmaxf(wm[2], wm[3]));
  const float scale = fmaxf(m / 127.0f, 1e-8f);
  const float inv = 1.0f / scale;
  if (tid == 0) scl[row] = scale;
  int8_t* qp = q + (size_t)row * rowlen;
  for (int i = tid * 4; i < rowlen; i += 1024) {
    const float4 v = *reinterpret_cast<const float4*>(rp + i);
    const int a = (int)rintf(fminf(fmaxf(v.x * inv, -127.f), 127.f));
    const int b = (int)rintf(fminf(fmaxf(v.y * inv, -127.f), 127.f));
    const int c = (int)rintf(fminf(fmaxf(v.z * inv, -127.f), 127.f));
    const int d = (int)rintf(fminf(fmaxf(v.w * inv, -127.f), 127.f));
    *reinterpret_cast<int*>(qp + i) =
        (a & 255) | ((b & 255) << 8) | ((c & 255) << 16) | (d << 24);
  }
}

// ---------------- per-row int8 quant of bf16 h (exact f32 absmax supplied) ----
__global__ __launch_bounds__(256) void quant_h_rows(
    const __hip_bfloat16* __restrict__ h, const int* __restrict__ amax,
    int8_t* __restrict__ q, float* __restrict__ scl) {
  const int row = blockIdx.x;
  const int tid = threadIdx.x;
  const float scale = fmaxf(__int_as_float(amax[row]) / 127.0f, 1e-8f);
  const float inv = 1.0f / scale;
  if (tid == 0) scl[row] = scale;
  const __hip_bfloat16* rp = h + (size_t)row * I_DIM;
  int8_t* qp = q + (size_t)row * I_DIM;
  for (int i = tid * 8; i < I_DIM; i += 2048) {
    const uint4 v = *reinterpret_cast<const uint4*>(rp + i);
    const uint32_t w[4] = {v.x, v.y, v.z, v.w};
    int pk0 = 0, pk1 = 0;
#pragma unroll
    for (int j = 0; j < 8; ++j) {
      const float f =
          __uint_as_float(((w[j >> 1] >> ((j & 1) * 16)) & 0xffffu) << 16);
      const int qv = (int)rintf(fminf(fmaxf(f * inv, -127.f), 127.f));
      if (j < 4) pk0 |= (qv & 255) << ((j & 3) * 8);
      else       pk1 |= (qv & 255) << ((j & 3) * 8);
    }
    *reinterpret_cast<int2*>(qp + i) = make_int2(pk0, pk1);
  }
}

// =====================================================================
// GEMM1 fused: 256x256 tile, BK=128, 8 waves, 4-phase/K-tile schedule,
// counted vmcnt(4), int8 MFMA, SiLU epilogue -> h(bf16) + row absmax.
// B tile = 128 gate rows (nh=0) + 128 up rows (nh=1) of the same h-cols.
// =====================================================================
__global__ __launch_bounds__(512, 2) void gemm1_silu(
    const int8_t* __restrict__ qx, const float* __restrict__ sx,
    const int8_t* __restrict__ qw, const float* __restrict__ sw,
    __hip_bfloat16* __restrict__ h, int* __restrict__ hmax) {
  __shared__ int8_t lds[131072];  // A: [0,64K) 2 bufs; B: [64K,128K) 2 bufs
  const int tid = threadIdx.x;
  const int lane = tid & 63;
  const int wid = tid >> 6;  // 0..7
  const int wr = wid >> 2;   // 0..1
  const int wc = wid & 3;    // 0..3
  const int c16 = lane & 15;
  const int kq = lane >> 4;
  const int r7 = lane & 7;
  const int lr = lane >> 3;
  const int sslot = ((lane & 7) ^ lr) << 4;
  const int sl0 = (kq ^ r7) << 4;
  const int sl1 = ((4 + kq) ^ r7) << 4;

  // bijective XCD swizzle (nwg % 8 == 0)
  const int nwg = gridDim.x;
  const int id = blockIdx.x;
  const int swz = (id & 7) * (nwg >> 3) + (id >> 3);
  const int NBN = I_DIM / 128;  // 44
  const int bm = swz / NBN;
  const int bn = swz % NBN;

  const size_t goffA = (size_t)(bm * 256 + wid * 8 + lr) * H_DIM + sslot;
  const size_t goffG = (size_t)(bn * 128 + wid * 8 + lr) * H_DIM + sslot;
  const size_t goffU = goffG + (size_t)I_DIM * H_DIM;
  const int ldsAw = wid * 8 * 128;
  const int ldsBw = 65536 + wid * 8 * 128;

  i32x4 acc[2][4][2][2] = {};  // [mh][m'][nh(gate/up)][n']

#define STAGE_A1(half, t)                                                      \
  do {                                                                         \
    const int _b = ((t) & 1) * 32768;                                          \
    _Pragma("unroll") for (int ld = 0; ld < 2; ++ld)                           \
        gload16(qx + goffA + (size_t)((half)*128 + ld * 64) * H_DIM +          \
                    (size_t)(t) * 128,                                         \
                lds + _b + ldsAw + ((half)*128 + ld * 64) * 128);              \
  } while (0)

#define STAGE_B1(half, t)                                                      \
  do {                                                                         \
    const int _b = ((t) & 1) * 32768;                                          \
    const int8_t* _s = (half) ? (qw + goffU) : (qw + goffG);                   \
    _Pragma("unroll") for (int ld = 0; ld < 2; ++ld)                           \
        gload16(_s + (size_t)(ld * 64) * H_DIM + (size_t)(t) * 128,            \
                lds + _b + ldsBw + ((half)*128 + ld * 64) * 128);              \
  } while (0)

#define LOAD_A1(MH)                                                            \
  do {                                                                         \
    _Pragma("unroll") for (int m = 0; m < 4; ++m) {                            \
      const int ar = (MH)*128 + wr * 64 + m * 16 + c16;                        \
      a[m][0] = *reinterpret_cast<const i32x4*>(lds + cb + ar * 128 + sl0);    \
      a[m][1] = *reinterpret_cast<const i32x4*>(lds + cb + ar * 128 + sl1);    \
    }                                                                          \
  } while (0)

#define LOAD_B1(NH)                                                            \
  do {                                                                         \
    _Pragma("unroll") for (int n = 0; n < 2; ++n) {                            \
      const int br = (NH)*128 + wc * 32 + n * 16 + c16;                        \
      b[NH][n][0] =                                                            \
          *reinterpret_cast<const i32x4*>(lds + 65536 + cb + br * 128 + sl0);  \
      b[NH][n][1] =                                                            \
          *reinterpret_cast<const i32x4*>(lds + 65536 + cb + br * 128 + sl1);  \
    }                                                                          \
  } while (0)

#define MFMA_Q1(MH, NH)                                                        \
  do {                                                                         \
    __builtin_amdgcn_s_setprio(1);                                             \
    _Pragma("unroll") for (int kk = 0; kk < 2; ++kk)                           \
        _Pragma("unroll") for (int m = 0; m < 4; ++m)                          \
            _Pragma("unroll") for (int n = 0; n < 2; ++n) acc[MH][m][NH][n] =  \
        __builtin_amdgcn_mfma_i32_16x16x64_i8(a[m][kk], b[NH][n][kk],          \
                                              acc[MH][m][NH][n], 0, 0, 0);     \
    __builtin_amdgcn_s_setprio(0);                                             \
  } while (0)

  const int KT = H_DIM / 128;  // 16
  // prologue: tile0 fully + tile1 A-h0/B-h0; keep 4 loads in flight
  STAGE_A1(0, 0); STAGE_B1(0, 0); STAGE_A1(1, 0); STAGE_B1(1, 0);
  STAGE_A1(0, 1); STAGE_B1(0, 1);
  asm volatile("s_waitcnt vmcnt(4)" ::: "memory");
  BAR();

#pragma unroll 1
  for (int t = 0; t < KT; ++t) {
    const int cb = (t & 1) * 32768;
    i32x4 a[4][2], b[2][2][2];
    // phase 0: quad (mh=0, nh=0)
    LOAD_A1(0); LOAD_B1(0);
    if (t + 1 < KT) STAGE_A1(1, t + 1);
    BAR();
    MFMA_Q1(0, 0);
    BAR();
    // phase 1: quad (0,1)
    LOAD_B1(1);
    if (t + 1 < KT) STAGE_B1(1, t + 1);
    BAR();
    MFMA_Q1(0, 1);
    BAR();
    // phase 2: quad (1,0)  (A-h0 of buf cb dead after phase 0 -> safe to overwrite)
    LOAD_A1(1);
    if (t + 2 < KT) STAGE_A1(0, t + 2);
    BAR();
    MFMA_Q1(1, 0);
    BAR();
    // phase 3: quad (1,1)  (B-h0 of buf cb dead after phase 0 reads -> safe)
    if (t + 2 < KT) STAGE_B1(0, t + 2);
    BAR();
    MFMA_Q1(1, 1);
    if (t + 2 < KT) asm volatile("s_waitcnt vmcnt(4)" ::: "memory");
    else            asm volatile("s_waitcnt vmcnt(0)" ::: "memory");
    BAR();
  }

  // epilogue: exact dequant, silu(g)*u, bf16 h write, exact-f32 row absmax
  const int row0 = bm * 256 + wr * 64 + kq * 4;
  const int col0 = bn * 128 + wc * 32 + c16;
#pragma unroll
  for (int mh = 0; mh < 2; ++mh) {
#pragma unroll
    for (int m = 0; m < 4; ++m) {
#pragma unroll
      for (int r = 0; r < 4; ++r) {
        const int row = row0 + mh * 128 + m * 16 + r;
        const float sxr = sx[row];
        float rmax = 0.f;
#pragma unroll
        for (int n = 0; n < 2; ++n) {
          const int col = col0 + n * 16;
          const float g = (float)acc[mh][m][0][n][r] * (sxr * sw[col]);
          const float u = (float)acc[mh][m][1][n][r] * (sxr * sw[I_DIM + col]);
          const float hv = g / (1.f + __expf(-g)) * u;
          h[(size_t)row * I_DIM + col] = __float2bfloat16(hv);
          rmax = fmaxf(rmax, fabsf(hv));
        }
#pragma unroll
        for (int o = 1; o < 16; o <<= 1)
          rmax = fmaxf(rmax, __shfl_xor(rmax, o));
        if (c16 == 0) atomicMax(hmax + row, __float_as_int(rmax));
      }
    }
  }
}

// =====================================================================
// GEMM2: 256x256 tile, BK=128, same 4-phase schedule, dequant -> f32 out
// =====================================================================
__global__ __launch_bounds__(512, 2) void gemm2(
    const int8_t* __restrict__ qh, const float* __restrict__ sh,
    const int8_t* __restrict__ qw, const float* __restrict__ sw,
    float* __restrict__ out) {
  __shared__ int8_t lds[131072];
  const int tid = threadIdx.x;
  const int lane = tid & 63;
  const int wid = tid >> 6;
  const int wr = wid >> 2;
  const int wc = wid & 3;
  const int c16 = lane & 15;
  const int kq = lane >> 4;
  const int r7 = lane & 7;
  const int lr = lane >> 3;
  const int sslot = ((lane & 7) ^ lr) << 4;
  const int sl0 = (kq ^ r7) << 4;
  const int sl1 = ((4 + kq) ^ r7) << 4;

  const int nwg = gridDim.x;  // 256
  const int id = blockIdx.x;
  const int swz = (id & 7) * (nwg >> 3) + (id >> 3);
  const int NBN = H_DIM / 256;  // 8
  const int bm = swz / NBN;
  const int bn = swz % NBN;

  const size_t goffA = (size_t)(bm * 256 + wid * 8 + lr) * I_DIM + sslot;
  const size_t goffB = (size_t)(bn * 256 + wid * 8 + lr) * I_DIM + sslot;
  const int ldsAw = wid * 8 * 128;
  const int ldsBw = 65536 + wid * 8 * 128;

  i32x4 acc[2][4][2][2] = {};  // [mh][m'][nh][n']

#define STAGE_A2(half, t)                                                      \
  do {                                                                         \
    const int _b = ((t) & 1) * 32768;                                          \
    _Pragma("unroll") for (int ld = 0; ld < 2; ++ld)                           \
        gload16(qh + goffA + (size_t)((half)*128 + ld * 64) * I_DIM +          \
                    (size_t)(t) * 128,                                         \
                lds + _b + ldsAw + ((half)*128 + ld * 64) * 128);              \
  } while (0)

#define STAGE_B2(half, t)                                                      \
  do {                                                                         \
    const int _b = ((t) & 1) * 32768;                                          \
    _Pragma("unroll") for (int ld = 0; ld < 2; ++ld)                           \
        gload16(qw + goffB + (size_t)((half)*128 + ld * 64) * I_DIM +          \
                    (size_t)(t) * 128,                                         \
                lds + _b + ldsBw + ((half)*128 + ld * 64) * 128);              \
  } while (0)

#define LOAD_A2(MH)                                                            \
  do {                                                                         \
    _Pragma("unroll") for (int m = 0; m < 4; ++m) {                            \
      const int ar = (MH)*128 + wr * 64 + m * 16 + c16;                        \
      a[m][0] = *reinterpret_cast<const i32x4*>(lds + cb + ar * 128 + sl0);    \
      a[m][1] = *reinterpret_cast<const i32x4*>(lds + cb + ar * 128 + sl1);    \
    }                                                                          \
  } while (0)

#define LOAD_B2(NH)                                                            \
  do {                                                                         \
    _Pragma("unroll") for (int n = 0; n < 2; ++n) {                            \
      const int br = (NH)*128 + wc * 32 + n * 16 + c16;                        \
      b[NH][n][0] =                                                            \
          *reinterpret_cast<const i32x4*>(lds + 65536 + cb + br * 128 + sl0);  \
      b[NH][n][1] =                                                            \
          *reinterpret_cast<const i32x4*>(lds + 65536 + cb + br * 128 + sl1);  \
    }                                                                          \
  } while (0)

#define MFMA_Q2(MH, NH)                                                        \
  do {                                                                         \
    __builtin_amdgcn_s_setprio(1);                                             \
    _Pragma("unroll") for (int kk = 0; kk < 2; ++kk)                           \
        _Pragma("unroll") for (int m = 0; m < 4; ++m)                          \
            _Pragma("unroll") for (int n = 0; n < 2; ++n) acc[MH][m][NH][n] =  \
        __builtin_amdgcn_mfma_i32_16x16x64_i8(a[m][kk], b[NH][n][kk],          \
                                              acc[MH][m][NH][n], 0, 0, 0);     \
    __builtin_amdgcn_s_setprio(0);                                             \
  } while (0)

  const int KT = I_DIM / 128;  // 44
  STAGE_A2(0, 0); STAGE_B2(0, 0); STAGE_A2(1, 0); STAGE_B2(1, 0);
  STAGE_A2(0, 1); STAGE_B2(0, 1);
  asm volatile("s_waitcnt vmcnt(4)" ::: "memory");
  BAR();

#pragma unroll 1
  for (int t = 0; t < KT; ++t) {
    const int cb = (t & 1) * 32768;
    i32x4 a[4][2], b[2][2][2];
    LOAD_A2(0); LOAD_B2(0);
    if (t + 1 < KT) STAGE_A2(1, t + 1);
    BAR();
    MFMA_Q2(0, 0);
    BAR();
    LOAD_B2(1);
    if (t + 1 < KT) STAGE_B2(1, t + 1);
    BAR();
    MFMA_Q2(0, 1);
    BAR();
    LOAD_A2(1);
    if (t + 2 < KT) STAGE_A2(0, t + 2);
    BAR();
    MFMA_Q2(1, 0);
    BAR();
    if (t + 2 < KT) STAGE_B2(0, t + 2);
    BAR();
    MFMA_Q2(1, 1);
    if (t + 2 < KT) asm volatile("s_waitcnt vmcnt(4)" ::: "memory");
    else            asm volatile("s_waitcnt vmcnt(0)" ::: "memory");
    BAR();
  }

  const int row0 = bm * 256 + wr * 64 + kq * 4;
  const int col0 = bn * 256 + wc * 32 + c16;
#pragma unroll
  for (int mh = 0; mh < 2; ++mh) {
#pragma unroll
    for (int m = 0; m < 4; ++m) {
#pragma unroll
      for (int r = 0; r < 4; ++r) {
        const int row = row0 + mh * 128 + m * 16 + r;
        const float shr = sh[row];
#pragma unroll
        for (int nh = 0; nh < 2; ++nh) {
#pragma unroll
          for (int n = 0; n < 2; ++n) {
            const int col = col0 + nh * 128 + n * 16;
            out[(size_t)row * H_DIM + col] =
                (float)acc[mh][m][nh][n][r] * (shr * sw[col]);
          }
        }
      }
    }
  }
}

extern "C" void kernel_launch(void* const* d_in, const int* in_sizes, int n_in,
                              void* d_out, int out_size, void* d_ws, size_t ws_size,
                              hipStream_t stream) {
  (void)in_sizes; (void)n_in; (void)out_size; (void)ws_size;
  const float* x  = (const float*)d_in[0];
  const float* w1 = (const float*)d_in[1];
  const float* w2 = (const float*)d_in[2];
  float* out = (float*)d_out;

  size_t off = 0;
  auto alloc = [&](size_t n) {
    void* p = (char*)d_ws + off;
    off += (n + 255) & ~(size_t)255;
    return p;
  };
  int8_t* qx  = (int8_t*)alloc((size_t)M_DIM * H_DIM);
  int8_t* qw1 = (int8_t*)alloc((size_t)N1_DIM * H_DIM);
  int8_t* qw2 = (int8_t*)alloc((size_t)H_DIM * I_DIM);
  int8_t* qh  = (int8_t*)alloc((size_t)M_DIM * I_DIM);
  __hip_bfloat16* hb = (__hip_bfloat16*)alloc((size_t)M_DIM * I_DIM * 2);
  float* sx  = (float*)alloc((size_t)M_DIM * 4);
  float* sw1 = (float*)alloc((size_t)N1_DIM * 4);
  float* sw2 = (float*)alloc((size_t)H_DIM * 4);
  float* shs = (float*)alloc((size_t)M_DIM * 4);
  int* hmax  = (int*)alloc((size_t)M_DIM * 4);

  hipMemsetAsync(hmax, 0, (size_t)M_DIM * 4, stream);
  quant_rows_f32<<<M_DIM, 256, 0, stream>>>(x, qx, sx, H_DIM);
  quant_rows_f32<<<N1_DIM, 256, 0, stream>>>(w1, qw1, sw1, H_DIM);
  quant_rows_f32<<<H_DIM, 256, 0, stream>>>(w2, qw2, sw2, I_DIM);
  gemm1_silu<<<(M_DIM / 256) * (I_DIM / 128), 512, 0, stream>>>(
      qx, sx, qw1, sw1, hb, hmax);
  quant_h_rows<<<M_DIM, 256, 0, stream>>>(hb, hmax, qh, shs);
  gemm2<<<(M_DIM / 256) * (H_DIM / 256), 512, 0, stream>>>(
      qh, shs, qw2, sw2, out);
}